// Round 6
// baseline (14039.418 us; speedup 1.0000x reference)
//
#include <hip/hip_runtime.h>
#include <hip/hip_cooperative_groups.h>
#include <math.h>

namespace cg = cooperative_groups;

#define NN     2048
#define NLVL   7
#define HD     16
#define HTOT   112
#define NB     64

// LDS union (floats):
//  panel:    Ld@0(64*65)  P@4160(64*65)  invd@8320(64)
//  syrk:     As@0(64*68)  Bs@4352(64*68)
//  solve128: LA@0(64*65)  LB@4160(64*65) yb@8320(128*16)
//  upd tile: Lt@0(64*129)              yk@8320(128*16)
#define LDS_FLOATS 10368

// ==================== cooperative-kernel device helpers ====================
__device__ void chol64_lds(float* s, int tid)
{
  for (int j = 0; j < 64; ++j) {
    float pj = s[j*68+j];
    __syncthreads();
    float inv = 1.0f / sqrtf(pj);
    if (tid == j) s[j*68+j] = sqrtf(pj);
    else if (tid > j && tid < 64) s[tid*68+j] *= inv;
    __syncthreads();
    int rr = j + 1 + (tid >> 2);
    if (rr < 64) {
      float lr = s[rr*68+j];
      for (int c = j + 1 + (tid & 3); c <= rr; c += 4)
        s[rr*68+c] -= lr * s[c*68+j];
    }
    __syncthreads();
  }
}

__device__ void panel_tile(float* __restrict__ A, int k, int r0, float* lds, int tid)
{
  float* Ld = lds; float* P = lds + 4160; float* invd = lds + 8320;
  for (int t = tid; t < 4096; t += 256) {
    int r = t >> 6, c = t & 63;
    Ld[r*65+c] = A[(size_t)(k + r) * NN + k + c];
    P [r*65+c] = A[(size_t)(r0 + r) * NN + k + c];
  }
  __syncthreads();
  if (tid < 64) invd[tid] = 1.0f / Ld[tid*65+tid];
  __syncthreads();
  if (tid < 64) {
    int r = tid;
    for (int j = 0; j < 64; ++j) {
      float acc = P[r*65+j];
      for (int p = 0; p < j; ++p) acc -= Ld[j*65+p] * P[r*65+p];
      P[r*65+j] = acc * invd[j];
    }
  }
  __syncthreads();
  for (int t = tid; t < 4096; t += 256) {
    int r = t >> 6, c = t & 63;
    A[(size_t)(r0 + r) * NN + k + c] = P[r*65+c];
  }
  __syncthreads();
}

__device__ void syrk_tile(float* __restrict__ A, int k, int i0, int j0,
                          float* lds, int tid, bool fuse)
{
  float* As = lds; float* Bs = lds + 4352;
  for (int t = tid; t < 4096; t += 256) {
    int r = t >> 6, c = t & 63;
    As[r*68+c] = A[(size_t)(i0 + r) * NN + k + c];
    Bs[r*68+c] = A[(size_t)(j0 + r) * NN + k + c];
  }
  __syncthreads();
  int tx = tid & 15, ty = tid >> 4;
  float acc[4][4] = {{0.f}};
  #pragma unroll
  for (int p4 = 0; p4 < 16; ++p4) {
    float4 av[4], bv[4];
    #pragma unroll
    for (int ii = 0; ii < 4; ++ii) av[ii] = *(const float4*)&As[(ty*4+ii)*68 + p4*4];
    #pragma unroll
    for (int jj = 0; jj < 4; ++jj) bv[jj] = *(const float4*)&Bs[(tx*4+jj)*68 + p4*4];
    #pragma unroll
    for (int ii = 0; ii < 4; ++ii)
      #pragma unroll
      for (int jj = 0; jj < 4; ++jj)
        acc[ii][jj] += av[ii].x*bv[jj].x + av[ii].y*bv[jj].y
                     + av[ii].z*bv[jj].z + av[ii].w*bv[jj].w;
  }
  if (!fuse) {
    #pragma unroll
    for (int ii = 0; ii < 4; ++ii) {
      float4* cp = (float4*)&A[(size_t)(i0 + ty*4 + ii) * NN + j0 + tx*4];
      float4 cv = *cp;
      cv.x -= acc[ii][0]; cv.y -= acc[ii][1]; cv.z -= acc[ii][2]; cv.w -= acc[ii][3];
      *cp = cv;
    }
    __syncthreads();
  } else {
    float4 cv[4];
    #pragma unroll
    for (int ii = 0; ii < 4; ++ii) {
      cv[ii] = *(const float4*)&A[(size_t)(i0 + ty*4 + ii) * NN + j0 + tx*4];
      cv[ii].x -= acc[ii][0]; cv[ii].y -= acc[ii][1];
      cv[ii].z -= acc[ii][2]; cv[ii].w -= acc[ii][3];
    }
    __syncthreads();
    #pragma unroll
    for (int ii = 0; ii < 4; ++ii)
      *(float4*)&As[(ty*4+ii)*68 + tx*4] = cv[ii];
    __syncthreads();
    chol64_lds(As, tid);
    for (int t = tid; t < 4096; t += 256) {
      int r = t >> 6, c = t & 63;
      A[(size_t)(i0 + r) * NN + i0 + c] = As[r*68+c];
    }
    __syncthreads();
  }
}

__device__ void solve128_fwd(const float* __restrict__ L, int kb, float* lds, int tid)
{
  float* LA = lds; float* LB = lds + 4160; float* yb = lds + 8320;
  for (int t = tid; t < 4096; t += 256) {
    int r = t >> 6, c = t & 63;
    LA[r*65+c] = L[(size_t)(kb + r) * NN + kb + c];
    LB[r*65+c] = L[(size_t)(kb + 64 + r) * NN + kb + c];
  }
  __syncthreads();
  if (tid < HD) {
    int c = tid;
    for (int j = 0; j < 64; ++j) {
      float acc = yb[j*HD + c];
      for (int p = 0; p < j; ++p) acc -= LA[j*65+p] * yb[p*HD + c];
      yb[j*HD + c] = acc / LA[j*65+j];
    }
  }
  __syncthreads();
  for (int o = tid; o < 1024; o += 256) {
    int r = o >> 4, c = o & 15;
    float acc = 0.f;
    #pragma unroll 8
    for (int p = 0; p < 64; ++p) acc += LB[r*65+p] * yb[p*HD + c];
    yb[(64+r)*HD + c] -= acc;
  }
  for (int t = tid; t < 4096; t += 256) {
    int r = t >> 6, c = t & 63;
    LA[r*65+c] = L[(size_t)(kb + 64 + r) * NN + (kb + 64) + c];
  }
  __syncthreads();
  if (tid < HD) {
    int c = tid;
    for (int j = 0; j < 64; ++j) {
      float acc = yb[(64+j)*HD + c];
      for (int p = 0; p < j; ++p) acc -= LA[j*65+p] * yb[(64+p)*HD + c];
      yb[(64+j)*HD + c] = acc / LA[j*65+j];
    }
  }
  __syncthreads();
}

__device__ void solve128_bwd(const float* __restrict__ L, int kb, float* lds, int tid)
{
  float* LA = lds; float* LB = lds + 4160; float* yb = lds + 8320;
  for (int t = tid; t < 4096; t += 256) {
    int r = t >> 6, c = t & 63;
    LA[r*65+c] = L[(size_t)(kb + 64 + r) * NN + (kb + 64) + c];
    LB[r*65+c] = L[(size_t)(kb + 64 + r) * NN + kb + c];
  }
  __syncthreads();
  if (tid < HD) {
    int c = tid;
    for (int j = 63; j >= 0; --j) {
      float acc = yb[(64+j)*HD + c];
      for (int p = j + 1; p < 64; ++p) acc -= LA[p*65+j] * yb[(64+p)*HD + c];
      yb[(64+j)*HD + c] = acc / LA[j*65+j];
    }
  }
  __syncthreads();
  for (int o = tid; o < 1024; o += 256) {
    int r = o >> 4, c = o & 15;
    float acc = 0.f;
    #pragma unroll 8
    for (int p = 0; p < 64; ++p) acc += LB[p*65+r] * yb[(64+p)*HD + c];
    yb[r*HD + c] -= acc;
  }
  for (int t = tid; t < 4096; t += 256) {
    int r = t >> 6, c = t & 63;
    LA[r*65+c] = L[(size_t)(kb + r) * NN + kb + c];
  }
  __syncthreads();
  if (tid < HD) {
    int c = tid;
    for (int j = 63; j >= 0; --j) {
      float acc = yb[j*HD + c];
      for (int p = j + 1; p < 64; ++p) acc -= LA[p*65+j] * yb[p*HD + c];
      yb[j*HD + c] = acc / LA[j*65+j];
    }
  }
  __syncthreads();
}

__device__ void upd_tile_fwd_c(const float* __restrict__ L, float* __restrict__ yl,
                               int kb, int r0, float* lds, int tid)
{
  float* Lt = lds; float* yk = lds + 8320;
  for (int e = tid; e < 8192; e += 256) {
    int r = e >> 7, p = e & 127;
    Lt[r*129+p] = L[(size_t)(r0 + r) * NN + kb + p];
  }
  for (int e = tid; e < 2048; e += 256) yk[e] = yl[(size_t)kb * HD + e];
  __syncthreads();
  int row = tid & 63, cgp = tid >> 6;
  float4 acc = make_float4(0.f,0.f,0.f,0.f);
  #pragma unroll 8
  for (int p = 0; p < 128; ++p) {
    float l = Lt[row*129+p];
    float4 yv = *(const float4*)&yk[p*HD + cgp*4];
    acc.x += l*yv.x; acc.y += l*yv.y; acc.z += l*yv.z; acc.w += l*yv.w;
  }
  float4* yp = (float4*)&yl[(size_t)(r0 + row) * HD + cgp*4];
  float4 cv = *yp;
  cv.x -= acc.x; cv.y -= acc.y; cv.z -= acc.z; cv.w -= acc.w;
  *yp = cv;
  __syncthreads();
}

__device__ void upd_tile_bwd_c(const float* __restrict__ L, float* __restrict__ yl,
                               int kb, int r0, float* lds, int tid)
{
  float* Lt = lds; float* yk = lds + 8320;
  for (int e = tid; e < 8192; e += 256) {
    int p = e >> 6, r = e & 63;
    Lt[r*129+p] = L[(size_t)(kb + p) * NN + r0 + r];
  }
  for (int e = tid; e < 2048; e += 256) yk[e] = yl[(size_t)kb * HD + e];
  __syncthreads();
  int row = tid & 63, cgp = tid >> 6;
  float4 acc = make_float4(0.f,0.f,0.f,0.f);
  #pragma unroll 8
  for (int p = 0; p < 128; ++p) {
    float l = Lt[row*129+p];
    float4 yv = *(const float4*)&yk[p*HD + cgp*4];
    acc.x += l*yv.x; acc.y += l*yv.y; acc.z += l*yv.z; acc.w += l*yv.w;
  }
  float4* yp = (float4*)&yl[(size_t)(r0 + row) * HD + cgp*4];
  float4 cv = *yp;
  cv.x -= acc.x; cv.y -= acc.y; cv.z -= acc.z; cv.w -= acc.w;
  *yp = cv;
  __syncthreads();
}

__device__ void fwd_step_diag(const float* __restrict__ L, float* __restrict__ yl,
                              int kb, float* lds, int tid)
{
  float* Lt = lds; float* yb = lds + 8320;
  int row = tid & 63, cgp = tid >> 6;
  float4 ynew[2];
  #pragma unroll
  for (int h = 0; h < 2; ++h) {
    int r0 = kb + 128 + h*64;
    for (int e = tid; e < 8192; e += 256) {
      int r = e >> 7, p = e & 127;
      Lt[r*129+p] = L[(size_t)(r0 + r) * NN + kb + p];
    }
    __syncthreads();
    float4 acc = make_float4(0.f,0.f,0.f,0.f);
    #pragma unroll 8
    for (int p = 0; p < 128; ++p) {
      float l = Lt[row*129+p];
      float4 yv = *(const float4*)&yb[p*HD + cgp*4];
      acc.x += l*yv.x; acc.y += l*yv.y; acc.z += l*yv.z; acc.w += l*yv.w;
    }
    float4 cv = *(const float4*)&yl[(size_t)(r0 + row) * HD + cgp*4];
    ynew[h] = make_float4(cv.x-acc.x, cv.y-acc.y, cv.z-acc.z, cv.w-acc.w);
    __syncthreads();
  }
  *(float4*)&yb[row*HD + cgp*4]      = ynew[0];
  *(float4*)&yb[(64+row)*HD + cgp*4] = ynew[1];
  __syncthreads();
  solve128_fwd(L, kb + 128, lds, tid);
  for (int t = tid; t < 2048; t += 256)
    yl[(size_t)(kb + 128) * HD + t] = yb[t];
}

__device__ void bwd_step_diag(const float* __restrict__ L, float* __restrict__ yl,
                              int kb, float* lds, int tid)
{
  float* Lt = lds; float* yb = lds + 8320;
  int row = tid & 63, cgp = tid >> 6;
  float4 ynew[2];
  #pragma unroll
  for (int h = 0; h < 2; ++h) {
    int r0 = kb - 128 + h*64;
    for (int e = tid; e < 8192; e += 256) {
      int p = e >> 6, r = e & 63;
      Lt[r*129+p] = L[(size_t)(kb + p) * NN + r0 + r];
    }
    __syncthreads();
    float4 acc = make_float4(0.f,0.f,0.f,0.f);
    #pragma unroll 8
    for (int p = 0; p < 128; ++p) {
      float l = Lt[row*129+p];
      float4 yv = *(const float4*)&yb[p*HD + cgp*4];
      acc.x += l*yv.x; acc.y += l*yv.y; acc.z += l*yv.z; acc.w += l*yv.w;
    }
    float4 cv = *(const float4*)&yl[(size_t)(r0 + row) * HD + cgp*4];
    ynew[h] = make_float4(cv.x-acc.x, cv.y-acc.y, cv.z-acc.z, cv.w-acc.w);
    __syncthreads();
  }
  *(float4*)&yb[row*HD + cgp*4]      = ynew[0];
  *(float4*)&yb[(64+row)*HD + cgp*4] = ynew[1];
  __syncthreads();
  solve128_bwd(L, kb - 128, lds, tid);
  for (int t = tid; t < 2048; t += 256)
    yl[(size_t)(kb - 128) * HD + t] = yb[t];
}

// ================= cooperative mega-kernel =================
__global__ __launch_bounds__(256, 2) void solve_all(
    float* __restrict__ K, float* __restrict__ Y,
    const float* __restrict__ tp, const float* __restrict__ alpha,
    const float* __restrict__ sigma, const float* __restrict__ W, int nl)
{
  cg::grid_group gg = cg::this_grid();
  __shared__ __align__(16) float lds[LDS_FLOATS];
  const int w = blockIdx.x, G = gridDim.x, tid = threadIdx.x;

  for (int lz = 0; lz < nl; ++lz) {
    const float* xt = tp + (size_t)lz * NN * 3;
    const float a_ = alpha[lz];
    const float is_ = 1.0f / sigma[lz];
    float* Kl = K + (size_t)lz * NN * NN;
    for (int idx = w * 256 + tid; idx < NN*NN; idx += G * 256) {
      int i = idx >> 11, j = idx & (NN - 1);
      float d0 = xt[i*3]-xt[j*3], d1 = xt[i*3+1]-xt[j*3+1], d2 = xt[i*3+2]-xt[j*3+2];
      float dd = d0*d0 + d1*d1 + d2*d2;
      float v = __expf(-sqrtf(fmaxf(dd, 1e-12f)) * is_);
      if (i == j) v += a_;
      Kl[idx] = v;
    }
  }
  for (int t = w * 256 + tid; t < nl * NN * HD; t += G * 256) Y[t] = W[t];
  gg.sync();

  if (w < nl) {
    float* A = K + (size_t)w * NN * NN;
    for (int t = tid; t < 4096; t += 256)
      lds[(t >> 6)*68 + (t & 63)] = A[(size_t)(t >> 6) * NN + (t & 63)];
    __syncthreads();
    chol64_lds(lds, tid);
    for (int t = tid; t < 4096; t += 256)
      A[(size_t)(t >> 6) * NN + (t & 63)] = lds[(t >> 6)*68 + (t & 63)];
  }
  gg.sync();

  for (int k = 0; k + 64 < NN; k += 64) {
    int t64 = (NN - k - 64) >> 6;
    for (int g = w; g < nl * t64; g += G) {
      int lz = g / t64, rt = g - lz * t64;
      panel_tile(K + (size_t)lz * NN * NN, k, k + 64 + rt * 64, lds, tid);
    }
    gg.sync();
    int T = t64 * (t64 + 1) / 2;
    if (w < nl) {
      syrk_tile(K + (size_t)w * NN * NN, k, k + 64, k + 64, lds, tid, true);
    } else if (T > 1) {
      int nd = nl * (T - 1);
      for (int g = w - nl; g < nd; g += G - nl) {
        int lz = g / (T - 1);
        int idx = 1 + g - lz * (T - 1);
        int i = (int)((sqrtf(8.0f * idx + 1.0f) - 1.0f) * 0.5f);
        while ((i + 1) * (i + 2) / 2 <= idx) ++i;
        while (i * (i + 1) / 2 > idx) --i;
        int j = idx - i * (i + 1) / 2;
        syrk_tile(K + (size_t)lz * NN * NN, k, k + 64 + i * 64, k + 64 + j * 64,
                  lds, tid, false);
      }
    }
    gg.sync();
  }

  if (w < nl) {
    float* yb = lds + 8320;
    float* yl = Y + (size_t)w * NN * HD;
    for (int t = tid; t < 2048; t += 256) yb[t] = yl[t];
    solve128_fwd(K + (size_t)w * NN * NN, 0, lds, tid);
    for (int t = tid; t < 2048; t += 256) yl[t] = yb[t];
  }
  gg.sync();
  for (int kb = 0; kb + 128 < NN; kb += 128) {
    if (w < nl) {
      fwd_step_diag(K + (size_t)w * NN * NN, Y + (size_t)w * NN * HD, kb, lds, tid);
    } else {
      int ntot = (NN - kb - 256) >> 6;
      if (ntot > 0) {
        for (int g = w - nl; g < nl * ntot; g += G - nl) {
          int lz = g / ntot, rt = g - lz * ntot;
          upd_tile_fwd_c(K + (size_t)lz * NN * NN, Y + (size_t)lz * NN * HD,
                         kb, kb + 256 + rt * 64, lds, tid);
        }
      }
    }
    gg.sync();
  }

  if (w < nl) {
    float* yb = lds + 8320;
    float* yl = Y + (size_t)w * NN * HD;
    solve128_bwd(K + (size_t)w * NN * NN, NN - 128, lds, tid);
    for (int t = tid; t < 2048; t += 256)
      yl[(size_t)(NN - 128) * HD + t] = yb[t];
  }
  gg.sync();
  for (int kb = NN - 128; kb >= 128; kb -= 128) {
    if (w < nl) {
      bwd_step_diag(K + (size_t)w * NN * NN, Y + (size_t)w * NN * HD, kb, lds, tid);
    } else {
      int ntot = (kb - 128) >> 6;
      if (ntot > 0) {
        for (int g = w - nl; g < nl * ntot; g += G - nl) {
          int lz = g / ntot, rt = g - lz * ntot;
          upd_tile_bwd_c(K + (size_t)lz * NN * NN, Y + (size_t)lz * NN * HD,
                         kb, rt * 64, lds, tid);
        }
      }
    }
    gg.sync();
  }
}

// ==================== stepped fallback kernels (R2, proven) ====================
__global__ __launch_bounds__(256) void build_K(
    const float* __restrict__ tp, const float* __restrict__ alpha,
    const float* __restrict__ sigma, float* __restrict__ K, int lvl0)
{
  int lz  = blockIdx.y;
  int lvl = lvl0 + lz;
  int idx = blockIdx.x * 256 + threadIdx.x;
  int i = idx >> 11, j = idx & (NN - 1);
  const float* xt = tp + (size_t)lvl * NN * 3;
  float d0 = xt[i*3]-xt[j*3], d1 = xt[i*3+1]-xt[j*3+1], d2 = xt[i*3+2]-xt[j*3+2];
  float dd = d0*d0 + d1*d1 + d2*d2;
  float v = __expf(-sqrtf(fmaxf(dd, 1e-12f)) / sigma[lvl]);
  if (i == j) v += alpha[lvl];
  K[(size_t)lz*NN*NN + idx] = v;
}

__global__ __launch_bounds__(64) void chol_diag(float* __restrict__ K, int k)
{
  int lz = blockIdx.x;
  float* A = K + (size_t)lz * NN * NN;
  __shared__ float s[64][65];
  int tid = threadIdx.x;
  #pragma unroll 4
  for (int r = 0; r < 64; ++r)
    s[r][tid] = A[(size_t)(k + r) * NN + k + tid];
  __syncthreads();
  for (int j = 0; j < 64; ++j) {
    float djj = s[j][j];
    float inv = 1.0f / sqrtf(djj);
    if (tid > j) s[tid][j] *= inv;
    __syncthreads();
    if (tid > j) {
      float fr = s[tid][j];
      for (int p = j + 1; p <= tid; ++p)
        s[tid][p] -= fr * s[p][j];
    }
    __syncthreads();
  }
  s[tid][tid] = sqrtf(s[tid][tid]);
  __syncthreads();
  #pragma unroll 4
  for (int r = 0; r < 64; ++r)
    A[(size_t)(k + r) * NN + k + tid] = s[r][tid];
}

__global__ __launch_bounds__(128) void panel_trsm(float* __restrict__ K, int k)
{
  int lz = blockIdx.y;
  float* A = K + (size_t)lz * NN * NN;
  __shared__ float Ld[64][65];
  __shared__ float invd[64];
  __shared__ float P[128][65];
  int tid = threadIdx.x;
  for (int t = tid; t < 4096; t += 128)
    Ld[t >> 6][t & 63] = A[(size_t)(k + (t >> 6)) * NN + k + (t & 63)];
  int rbase = k + NB + blockIdx.x * 128;
  for (int t = tid; t < 128 * 64; t += 128) {
    int r = t >> 6, c = t & 63;
    if (rbase + r < NN) P[r][c] = A[(size_t)(rbase + r) * NN + k + c];
  }
  __syncthreads();
  if (tid < 64) invd[tid] = 1.0f / Ld[tid][tid];
  __syncthreads();
  int r = tid;
  if (rbase + r < NN) {
    for (int j = 0; j < 64; ++j) {
      float acc = P[r][j];
      for (int p = 0; p < j; ++p) acc -= Ld[j][p] * P[r][p];
      P[r][j] = acc * invd[j];
    }
  }
  __syncthreads();
  for (int t = tid; t < 128 * 64; t += 128) {
    int rr = t >> 6, c = t & 63;
    if (rbase + rr < NN) A[(size_t)(rbase + rr) * NN + k + c] = P[rr][c];
  }
}

__global__ __launch_bounds__(256) void syrk_update(float* __restrict__ K, int k)
{
  if (blockIdx.y > blockIdx.x) return;
  int lz = blockIdx.z;
  float* A = K + (size_t)lz * NN * NN;
  int i0 = k + NB + blockIdx.x * 64;
  int j0 = k + NB + blockIdx.y * 64;
  __shared__ __align__(16) float Asub[64][68];
  __shared__ __align__(16) float Bsub[64][68];
  int tid = threadIdx.x;
  for (int t = tid; t < 4096; t += 256) {
    int r = t >> 6, c = t & 63;
    Asub[r][c] = A[(size_t)(i0 + r) * NN + k + c];
    Bsub[r][c] = A[(size_t)(j0 + r) * NN + k + c];
  }
  __syncthreads();
  int tx = tid & 15, ty = tid >> 4;
  float acc[4][4] = {{0.f}};
  #pragma unroll
  for (int p4 = 0; p4 < 16; ++p4) {
    float4 av[4], bv[4];
    #pragma unroll
    for (int ii = 0; ii < 4; ++ii) av[ii] = *(const float4*)&Asub[ty*4+ii][p4*4];
    #pragma unroll
    for (int jj = 0; jj < 4; ++jj) bv[jj] = *(const float4*)&Bsub[tx*4+jj][p4*4];
    #pragma unroll
    for (int ii = 0; ii < 4; ++ii)
      #pragma unroll
      for (int jj = 0; jj < 4; ++jj)
        acc[ii][jj] += av[ii].x*bv[jj].x + av[ii].y*bv[jj].y
                     + av[ii].z*bv[jj].z + av[ii].w*bv[jj].w;
  }
  #pragma unroll
  for (int ii = 0; ii < 4; ++ii) {
    int row = i0 + ty*4 + ii;
    float4* cp = (float4*)&A[(size_t)row * NN + j0 + tx*4];
    float4 cv = *cp;
    cv.x -= acc[ii][0]; cv.y -= acc[ii][1]; cv.z -= acc[ii][2]; cv.w -= acc[ii][3];
    *cp = cv;
  }
}

__global__ __launch_bounds__(512) void trsm_diag_fwd(
    const float* __restrict__ K, float* __restrict__ Y, int kb)
{
  int lz = blockIdx.x;
  const float* L = K + (size_t)lz * NN * NN;
  float* y = Y + (size_t)lz * NN * HD;
  __shared__ float Ld1[64][65];
  __shared__ float L21[64][65];
  __shared__ float Ld2[64][65];
  __shared__ float yb[128][HD];
  int tid = threadIdx.x;
  for (int t = tid; t < 4096; t += 512) {
    int r = t >> 6, c = t & 63;
    Ld1[r][c] = L[(size_t)(kb + r) * NN + kb + c];
    L21[r][c] = L[(size_t)(kb + 64 + r) * NN + kb + c];
    Ld2[r][c] = L[(size_t)(kb + 64 + r) * NN + kb + 64 + c];
  }
  for (int t = tid; t < 128 * HD; t += 512)
    yb[t >> 4][t & 15] = y[(size_t)kb * HD + t];
  __syncthreads();
  if (tid < HD) {
    int c = tid;
    for (int j = 0; j < 64; ++j) {
      float acc = yb[j][c];
      for (int p = 0; p < j; ++p) acc -= Ld1[j][p] * yb[p][c];
      yb[j][c] = acc / Ld1[j][j];
    }
  }
  __syncthreads();
  {
    int o = tid;
    #pragma unroll
    for (int q = 0; q < 2; ++q, o += 512) {
      int r = o >> 4, c = o & 15;
      float acc = 0.f;
      #pragma unroll 16
      for (int p = 0; p < 64; ++p) acc += L21[r][p] * yb[p][c];
      yb[64 + r][c] -= acc;
    }
  }
  __syncthreads();
  if (tid < HD) {
    int c = tid;
    for (int j = 0; j < 64; ++j) {
      float acc = yb[64 + j][c];
      for (int p = 0; p < j; ++p) acc -= Ld2[j][p] * yb[64 + p][c];
      yb[64 + j][c] = acc / Ld2[j][j];
    }
  }
  __syncthreads();
  for (int t = tid; t < 128 * HD; t += 512)
    y[(size_t)kb * HD + t] = yb[t >> 4][t & 15];
}

__global__ __launch_bounds__(256) void trsm_upd_fwd(
    const float* __restrict__ K, float* __restrict__ Y, int kb)
{
  int lz = blockIdx.y;
  const float* L = K + (size_t)lz * NN * NN;
  float* y = Y + (size_t)lz * NN * HD;
  int i0 = kb + 128 + blockIdx.x * 64;
  __shared__ float Lt[64][129];
  __shared__ __align__(16) float yk[128][HD];
  int tid = threadIdx.x;
  for (int e = tid; e < 64 * 128; e += 256) {
    int r = e >> 7, p = e & 127;
    Lt[r][p] = L[(size_t)(i0 + r) * NN + kb + p];
  }
  for (int e = tid; e < 128 * HD; e += 256)
    yk[e >> 4][e & 15] = y[(size_t)kb * HD + e];
  __syncthreads();
  int row = tid & 63, cg2 = tid >> 6;
  float4 acc = make_float4(0.f, 0.f, 0.f, 0.f);
  #pragma unroll 8
  for (int p = 0; p < 128; ++p) {
    float l = Lt[row][p];
    float4 yv = *(const float4*)&yk[p][cg2 * 4];
    acc.x += l * yv.x; acc.y += l * yv.y; acc.z += l * yv.z; acc.w += l * yv.w;
  }
  float4* yp = (float4*)&y[(size_t)(i0 + row) * HD + cg2 * 4];
  float4 cv = *yp;
  cv.x -= acc.x; cv.y -= acc.y; cv.z -= acc.z; cv.w -= acc.w;
  *yp = cv;
}

__global__ __launch_bounds__(512) void trsm_diag_bwd(
    const float* __restrict__ K, float* __restrict__ Y, int kb)
{
  int lz = blockIdx.x;
  const float* L = K + (size_t)lz * NN * NN;
  float* y = Y + (size_t)lz * NN * HD;
  __shared__ float Ld1[64][65];
  __shared__ float L21[64][65];
  __shared__ float Ld2[64][65];
  __shared__ float yb[128][HD];
  int tid = threadIdx.x;
  for (int t = tid; t < 4096; t += 512) {
    int r = t >> 6, c = t & 63;
    Ld1[r][c] = L[(size_t)(kb + r) * NN + kb + c];
    L21[r][c] = L[(size_t)(kb + 64 + r) * NN + kb + c];
    Ld2[r][c] = L[(size_t)(kb + 64 + r) * NN + kb + 64 + c];
  }
  for (int t = tid; t < 128 * HD; t += 512)
    yb[t >> 4][t & 15] = y[(size_t)kb * HD + t];
  __syncthreads();
  if (tid < HD) {
    int c = tid;
    for (int j = 63; j >= 0; --j) {
      float acc = yb[64 + j][c];
      for (int p = j + 1; p < 64; ++p) acc -= Ld2[p][j] * yb[64 + p][c];
      yb[64 + j][c] = acc / Ld2[j][j];
    }
  }
  __syncthreads();
  {
    int o = tid;
    #pragma unroll
    for (int q = 0; q < 2; ++q, o += 512) {
      int r = o >> 4, c = o & 15;
      float acc = 0.f;
      #pragma unroll 16
      for (int p = 0; p < 64; ++p) acc += L21[p][r] * yb[64 + p][c];
      yb[r][c] -= acc;
    }
  }
  __syncthreads();
  if (tid < HD) {
    int c = tid;
    for (int j = 63; j >= 0; --j) {
      float acc = yb[j][c];
      for (int p = j + 1; p < 64; ++p) acc -= Ld1[p][j] * yb[p][c];
      yb[j][c] = acc / Ld1[j][j];
    }
  }
  __syncthreads();
  for (int t = tid; t < 128 * HD; t += 512)
    y[(size_t)kb * HD + t] = yb[t >> 4][t & 15];
}

__global__ __launch_bounds__(256) void trsm_upd_bwd(
    const float* __restrict__ K, float* __restrict__ Y, int kb)
{
  int lz = blockIdx.y;
  const float* L = K + (size_t)lz * NN * NN;
  float* y = Y + (size_t)lz * NN * HD;
  int i0 = blockIdx.x * 64;
  __shared__ float Lt[64][129];
  __shared__ __align__(16) float yk[128][HD];
  int tid = threadIdx.x;
  for (int e = tid; e < 64 * 128; e += 256) {
    int p = e >> 6, r = e & 63;
    Lt[r][p] = L[(size_t)(kb + p) * NN + i0 + r];
  }
  for (int e = tid; e < 128 * HD; e += 256)
    yk[e >> 4][e & 15] = y[(size_t)kb * HD + e];
  __syncthreads();
  int row = tid & 63, cg2 = tid >> 6;
  float4 acc = make_float4(0.f, 0.f, 0.f, 0.f);
  #pragma unroll 8
  for (int p = 0; p < 128; ++p) {
    float l = Lt[row][p];
    float4 yv = *(const float4*)&yk[p][cg2 * 4];
    acc.x += l * yv.x; acc.y += l * yv.y; acc.z += l * yv.z; acc.w += l * yv.w;
  }
  float4* yp = (float4*)&y[(size_t)(i0 + row) * HD + cg2 * 4];
  float4 cv = *yp;
  cv.x -= acc.x; cv.y -= acc.y; cv.z -= acc.z; cv.w -= acc.w;
  *yp = cv;
}

// ---------------- fused h^T and MLP ----------------
__global__ __launch_bounds__(256) void compute_h(
    const float* __restrict__ x, const float* __restrict__ tp,
    const float* __restrict__ A, const float* __restrict__ sigma,
    float* __restrict__ Ht, int N)
{
  int l = blockIdx.y;
  const float* xt = tp + (size_t)l * NN * 3;
  const float* al = A + (size_t)l * NN * HD;
  float inv_sigma = 1.0f / sigma[l];
  int tid = threadIdx.x;
  int r = blockIdx.x * 256 + tid;
  float x0 = 0.f, x1 = 0.f, x2 = 0.f;
  if (r < N) { x0 = x[r*3]; x1 = x[r*3+1]; x2 = x[r*3+2]; }
  __shared__ float sxt[128*3];
  __shared__ __align__(16) float sa[128*16];
  float acc[16] = {0.f};
  for (int jc = 0; jc < NN; jc += 128) {
    __syncthreads();
    for (int t = tid; t < 384; t += 256)  sxt[t] = xt[jc*3 + t];
    for (int t = tid; t < 2048; t += 256) sa[t]  = al[jc*16 + t];
    __syncthreads();
    #pragma unroll 2
    for (int jl = 0; jl < 128; ++jl) {
      float t0 = sxt[jl*3+0], t1 = sxt[jl*3+1], t2 = sxt[jl*3+2];
      float da = x0 - t0, db = x1 - t1, dc = x2 - t2;
      float d2 = da*da + db*db + dc*dc;
      float kv = __expf(-sqrtf(fmaxf(d2, 1e-12f)) * inv_sigma);
      const float4* a4 = (const float4*)&sa[jl*16];
      #pragma unroll
      for (int q = 0; q < 4; ++q) {
        float4 av = a4[q];
        acc[q*4+0] += kv*av.x; acc[q*4+1] += kv*av.y;
        acc[q*4+2] += kv*av.z; acc[q*4+3] += kv*av.w;
      }
    }
  }
  if (r < N) {
    #pragma unroll
    for (int hh = 0; hh < 16; ++hh) Ht[(size_t)(l*HD + hh) * N + r] = acc[hh];
  }
}

__global__ __launch_bounds__(256) void mlp_kernel(
    const float* __restrict__ Ht,
    const float* __restrict__ w1, const float* __restrict__ b1,
    const float* __restrict__ w2, const float* __restrict__ b2,
    const float* __restrict__ w3, const float* __restrict__ b3,
    const float* __restrict__ w4, const float* __restrict__ b4,
    const float* __restrict__ w5, const float* __restrict__ b5,
    float* __restrict__ out, int N)
{
  __shared__ __align__(16) float W1[HTOT*40];
  __shared__ __align__(16) float W2[1600];
  __shared__ __align__(16) float W3[1600];
  __shared__ __align__(16) float W4[1600];
  __shared__ float W5[40], B1[40], B2[40], B3[40], B4[40];
  __shared__ float B5s;
  int tid = threadIdx.x;
  for (int t = tid; t < HTOT*40; t += 256) W1[t] = w1[t];
  for (int t = tid; t < 1600; t += 256) { W2[t] = w2[t]; W3[t] = w3[t]; W4[t] = w4[t]; }
  if (tid < 40) { B1[tid]=b1[tid]; B2[tid]=b2[tid]; B3[tid]=b3[tid]; B4[tid]=b4[tid]; W5[tid]=w5[tid]; }
  if (tid == 0) B5s = b5[0];
  __syncthreads();
  int r = blockIdx.x * 256 + tid;
  if (r >= N) return;

  float za[40], zb[40];
  #pragma unroll
  for (int o = 0; o < 40; ++o) za[o] = B1[o];
  for (int i = 0; i < HTOT; ++i) {
    float hv = Ht[(size_t)i * N + r];
    const float4* wp = (const float4*)&W1[i*40];
    #pragma unroll
    for (int q = 0; q < 10; ++q) {
      float4 wv = wp[q];
      za[q*4+0] += hv*wv.x; za[q*4+1] += hv*wv.y; za[q*4+2] += hv*wv.z; za[q*4+3] += hv*wv.w;
    }
  }
  #pragma unroll
  for (int o = 0; o < 40; ++o) { za[o] = fmaxf(za[o], 0.f); zb[o] = B2[o]; }
  for (int i = 0; i < 40; ++i) {
    float hv = za[i];
    const float4* wp = (const float4*)&W2[i*40];
    #pragma unroll
    for (int q = 0; q < 10; ++q) {
      float4 wv = wp[q];
      zb[q*4+0] += hv*wv.x; zb[q*4+1] += hv*wv.y; zb[q*4+2] += hv*wv.z; zb[q*4+3] += hv*wv.w;
    }
  }
  #pragma unroll
  for (int o = 0; o < 40; ++o) { zb[o] = fmaxf(zb[o], 0.f); za[o] = B3[o]; }
  for (int i = 0; i < 40; ++i) {
    float hv = zb[i];
    const float4* wp = (const float4*)&W3[i*40];
    #pragma unroll
    for (int q = 0; q < 10; ++q) {
      float4 wv = wp[q];
      za[q*4+0] += hv*wv.x; za[q*4+1] += hv*wv.y; za[q*4+2] += hv*wv.z; za[q*4+3] += hv*wv.w;
    }
  }
  #pragma unroll
  for (int o = 0; o < 40; ++o) { za[o] = fmaxf(za[o], 0.f); zb[o] = B4[o]; }
  for (int i = 0; i < 40; ++i) {
    float hv = za[i];
    const float4* wp = (const float4*)&W4[i*40];
    #pragma unroll
    for (int q = 0; q < 10; ++q) {
      float4 wv = wp[q];
      zb[q*4+0] += hv*wv.x; zb[q*4+1] += hv*wv.y; zb[q*4+2] += hv*wv.z; zb[q*4+3] += hv*wv.w;
    }
  }
  float ov = B5s;
  #pragma unroll
  for (int o = 0; o < 40; ++o) ov += fmaxf(zb[o], 0.f) * W5[o];
  out[r] = ov;
}

// ---------------- host ----------------
static void run_chol_steps(float* K, int nl, hipStream_t stream)
{
  for (int k = 0; k < NN; k += NB) {
    chol_diag<<<nl, 64, 0, stream>>>(K, k);
    int m = NN - k - NB;
    if (m > 0) {
      panel_trsm<<<dim3((m + 127) / 128, nl), 128, 0, stream>>>(K, k);
      int t = m / 64;
      syrk_update<<<dim3(t, t, nl), 256, 0, stream>>>(K, k);
    }
  }
}

static void run_trsm_steps(const float* K, float* Y, int nl, hipStream_t stream)
{
  for (int kb = 0; kb < NN; kb += 128) {
    trsm_diag_fwd<<<nl, 512, 0, stream>>>(K, Y, kb);
    int m = NN - kb - 128;
    if (m > 0)
      trsm_upd_fwd<<<dim3(m / 64, nl), 256, 0, stream>>>(K, Y, kb);
  }
  for (int kb = NN - 128; kb >= 0; kb -= 128) {
    trsm_diag_bwd<<<nl, 512, 0, stream>>>(K, Y, kb);
    if (kb > 0)
      trsm_upd_bwd<<<dim3(kb / 64, nl), 256, 0, stream>>>(K, Y, kb);
  }
}

extern "C" void kernel_launch(void* const* d_in, const int* in_sizes, int n_in,
                              void* d_out, int out_size, void* d_ws, size_t ws_size,
                              hipStream_t stream)
{
  (void)n_in; (void)out_size;
  const float* x     = (const float*)d_in[0];
  const float* tp    = (const float*)d_in[1];
  const float* W     = (const float*)d_in[2];
  const float* alpha = (const float*)d_in[3];
  const float* sigma = (const float*)d_in[4];
  const float* w1 = (const float*)d_in[5];  const float* b1 = (const float*)d_in[6];
  const float* w2 = (const float*)d_in[7];  const float* b2 = (const float*)d_in[8];
  const float* w3 = (const float*)d_in[9];  const float* b3 = (const float*)d_in[10];
  const float* w4 = (const float*)d_in[11]; const float* b4 = (const float*)d_in[12];
  const float* w5 = (const float*)d_in[13]; const float* b5 = (const float*)d_in[14];
  float* out = (float*)d_out;
  int N = in_sizes[0] / 3;

  size_t kElems1 = (size_t)NN * NN;
  size_t aElems  = (size_t)NLVL * NN * HD;
  size_t hElems  = (size_t)N * HTOT;
  size_t need7   = (NLVL * kElems1 + aElems + hElems) * sizeof(float);
  bool batched = ws_size >= need7;

  float* K; float* Y; float* H;
  if (batched) {
    K = (float*)d_ws; Y = K + NLVL * kElems1; H = Y + aElems;
  } else {
    K = (float*)d_ws; Y = K + kElems1;        H = Y + aElems;
  }

  // --- try the cooperative mega-kernel, sized by the runtime's occupancy ---
  bool coop_done = false;
  if (batched) {
    int dev = 0;
    (void)hipGetDevice(&dev);
    hipDeviceProp_t prop;
    hipError_t pe = hipGetDeviceProperties(&prop, dev);
    int maxB = 0;
    hipError_t oe = hipOccupancyMaxActiveBlocksPerMultiprocessor(&maxB, solve_all, 256, 0);
    if (pe == hipSuccess && oe == hipSuccess) {
      long coopMax = (long)maxB * (long)prop.multiProcessorCount;
      int G = (int)(coopMax < 512 ? coopMax : 512);
      if (G >= 16) {
        int nlv = NLVL;
        void* args[] = { (void*)&K, (void*)&Y, (void*)&tp, (void*)&alpha,
                         (void*)&sigma, (void*)&W, (void*)&nlv };
        hipError_t le = hipLaunchCooperativeKernel((void*)solve_all, dim3(G),
                                                   dim3(256), args, 0, stream);
        if (le == hipSuccess) coop_done = true;
      }
    }
  }

  // --- fallback: proven stepped path (R2) ---
  if (!coop_done) {
    hipMemcpyAsync(Y, W, aElems * sizeof(float), hipMemcpyDeviceToDevice, stream);
    if (batched) {
      build_K<<<dim3((unsigned)(kElems1 / 256), NLVL), 256, 0, stream>>>(tp, alpha, sigma, K, 0);
      run_chol_steps(K, NLVL, stream);
      run_trsm_steps(K, Y, NLVL, stream);
    } else {
      for (int l = 0; l < NLVL; ++l) {
        build_K<<<dim3((unsigned)(kElems1 / 256), 1), 256, 0, stream>>>(tp, alpha, sigma, K, l);
        run_chol_steps(K, 1, stream);
        run_trsm_steps(K, Y + (size_t)l * NN * HD, 1, stream);
      }
    }
  }

  compute_h<<<dim3((N + 255) / 256, NLVL), 256, 0, stream>>>(x, tp, Y, sigma, H, N);
  mlp_kernel<<<(N + 255) / 256, 256, 0, stream>>>(H, w1, b1, w2, b2, w3, b3,
                                                  w4, b4, w5, b5, out, N);
}